// Round 1
// baseline (213.560 us; speedup 1.0000x reference)
//
#include <hip/hip_runtime.h>
#include <hip/hip_bf16.h>
#include <stdint.h>

typedef __bf16 bf16x8 __attribute__((ext_vector_type(8)));
typedef __bf16 bf16x4 __attribute__((ext_vector_type(4)));
typedef float f32x4 __attribute__((ext_vector_type(4)));

#define DEV __device__ __forceinline__

DEV void gload_lds16(const void* g, void* l) {
  __builtin_amdgcn_global_load_lds((const __attribute__((address_space(1))) void*)g,
                                   (__attribute__((address_space(3))) void*)l, 16, 0, 0);
}

// ---------------- pack x: f32 -> bf16 ----------------
__global__ __launch_bounds__(256) void pack_x_kernel(const float* __restrict__ x,
                                                     __bf16* __restrict__ o, long n) {
  long i = ((long)blockIdx.x * 256 + threadIdx.x) * 4;
  const long stride = (long)gridDim.x * 256 * 4;
  for (; i < n; i += stride) {
    f32x4 v = *(const f32x4*)(x + i);
    bf16x4 b;
    b[0] = (__bf16)v[0]; b[1] = (__bf16)v[1]; b[2] = (__bf16)v[2]; b[3] = (__bf16)v[3];
    *(bf16x4*)(o + i) = b;
  }
}

// ---------------- pack W: [1024][1024] f32 -> Wt[e][d] bf16 (Wq scaled 1/32) ----------------
__global__ __launch_bounds__(256) void pack_w_kernel(const float* __restrict__ Wq,
                                                     const float* __restrict__ Wk,
                                                     const float* __restrict__ Wv,
                                                     __bf16* __restrict__ Wt) {
  const int w = blockIdx.z;
  const float* W = (w == 0) ? Wq : (w == 1) ? Wk : Wv;
  const float scale = (w == 0) ? 0.03125f : 1.0f;
  const int d0 = blockIdx.x * 64;
  const int e0 = blockIdx.y * 64;
  __shared__ __bf16 T[64][72];
  const int tid = threadIdx.x;
  const int r4 = tid >> 4;
  const int c4 = (tid & 15) * 4;
#pragma unroll
  for (int p = 0; p < 4; ++p) {
    int r = r4 + p * 16;
    f32x4 v = *(const f32x4*)(W + (long)(d0 + r) * 1024 + e0 + c4);
    T[r][c4 + 0] = (__bf16)(v[0] * scale);
    T[r][c4 + 1] = (__bf16)(v[1] * scale);
    T[r][c4 + 2] = (__bf16)(v[2] * scale);
    T[r][c4 + 3] = (__bf16)(v[3] * scale);
  }
  __syncthreads();
  const int e4 = tid >> 3;
  const int dd = (tid & 7) * 8;
#pragma unroll
  for (int p = 0; p < 2; ++p) {
    int e = e4 + p * 32;
    bf16x8 ov;
#pragma unroll
    for (int j = 0; j < 8; ++j) ov[j] = T[dd + j][e];
    *(bf16x8*)(Wt + (long)w * 1048576 + (long)(e0 + e) * 1024 + d0 + dd) = ov;
  }
}

// ---------------- pack bias: concat, bq scaled 1/32, stays f32 ----------------
__global__ __launch_bounds__(256) void pack_bias_kernel(const float* __restrict__ bq,
                                                        const float* __restrict__ bk,
                                                        const float* __restrict__ bv,
                                                        float* __restrict__ o) {
  int i = blockIdx.x * 256 + threadIdx.x;
  if (i < 1024) o[i] = bq[i] * 0.03125f;
  else if (i < 2048) o[i] = bk[i - 1024];
  else if (i < 3072) o[i] = bv[i - 2048];
}

// ---------------- GEMM C[M,N] = A[M,K] * Bt[N,K]^T (+bias), bf16 in, f32/bf16 out -------------
// 128x128 tile, BK=64, 4 waves (2x2), each wave 64x64 via 4x4 mfma_16x16x32_bf16 frags.
// global_load_lds width-16 staging; XOR chunk swizzle on global source + ds_read addr.
template <bool OUT_BF16, bool BIAS>
__global__ __launch_bounds__(256) void gemm_bt_kernel(
    const __bf16* __restrict__ A, int lda, long long sAb,
    const __bf16* __restrict__ B, int ldb, long long sBb,
    const float* __restrict__ bias,
    void* __restrict__ C, int ldc, long long sCbBytes,
    int nbx, int k64) {
  __shared__ __attribute__((aligned(16))) __bf16 As[128 * 64];
  __shared__ __attribute__((aligned(16))) __bf16 Bs[128 * 64];
  const int tid = threadIdx.x;
  const int lane = tid & 63;
  const int wid = tid >> 6;
  const int wr = wid >> 1, wc = wid & 1;
  const int bm = blockIdx.x / nbx, bn = blockIdx.x % nbx;
  const long long b = blockIdx.z;
  A += b * sAb;
  B += b * sBb;

  const char* gA[4];
  const char* gB[4];
  int ldsOff[4];
#pragma unroll
  for (int i = 0; i < 4; ++i) {
    int q = (wid * 4 + i) * 64 + lane;  // 16B chunk index 0..1023
    int r = q >> 3, cc = q & 7;
    int sc = cc ^ (r & 7);              // inverse-swizzled global source chunk
    gA[i] = (const char*)(A + (long long)(bm * 128 + r) * lda + sc * 8);
    gB[i] = (const char*)(B + (long long)(bn * 128 + r) * ldb + sc * 8);
    ldsOff[i] = (wid * 4 + i) * 1024 + lane * 16;  // linear LDS dest
  }

  f32x4 acc[4][4] = {};
  const int lo = lane & 15, hi = lane >> 4;

  for (int kt = 0; kt < k64; ++kt) {
    const long long koff = (long long)kt * 128;  // 64 bf16 = 128 bytes
#pragma unroll
    for (int i = 0; i < 4; ++i) gload_lds16(gA[i] + koff, (char*)As + ldsOff[i]);
#pragma unroll
    for (int i = 0; i < 4; ++i) gload_lds16(gB[i] + koff, (char*)Bs + ldsOff[i]);
    __syncthreads();
#pragma unroll
    for (int ks = 0; ks < 2; ++ks) {
      bf16x8 av[4], bvv[4];
      const int chunk = ks * 4 + hi;
#pragma unroll
      for (int mi = 0; mi < 4; ++mi) {
        int r = wr * 64 + mi * 16 + lo;
        av[mi] = *(const bf16x8*)((const char*)As + r * 128 + ((chunk ^ (lo & 7)) << 4));
      }
#pragma unroll
      for (int ni = 0; ni < 4; ++ni) {
        int r = wc * 64 + ni * 16 + lo;
        bvv[ni] = *(const bf16x8*)((const char*)Bs + r * 128 + ((chunk ^ (lo & 7)) << 4));
      }
#pragma unroll
      for (int mi = 0; mi < 4; ++mi)
#pragma unroll
        for (int ni = 0; ni < 4; ++ni)
          acc[mi][ni] = __builtin_amdgcn_mfma_f32_16x16x32_bf16(av[mi], bvv[ni], acc[mi][ni], 0, 0, 0);
    }
    __syncthreads();
  }

  // epilogue: C/D map col=lane&15, row=(lane>>4)*4+j  [m89-verified]
  char* Cb = (char*)C + b * sCbBytes;
  const long long row0 = (long long)bm * 128 + wr * 64;
  const long long col0 = (long long)bn * 128 + wc * 64;
#pragma unroll
  for (int ni = 0; ni < 4; ++ni) {
    const long long col = col0 + ni * 16 + lo;
    const float bvs = BIAS ? bias[col] : 0.0f;
#pragma unroll
    for (int mi = 0; mi < 4; ++mi) {
#pragma unroll
      for (int j = 0; j < 4; ++j) {
        long long row = row0 + mi * 16 + hi * 4 + j;
        float v = acc[mi][ni][j] + bvs;
        if (OUT_BF16)
          ((__bf16*)Cb)[row * ldc + col] = (__bf16)v;
        else
          ((float*)Cb)[row * ldc + col] = v;
      }
    }
  }
}

// ---------------- transpose V (from QKV col block 2048..3071) -> Vt[b][e][t] ----------------
__global__ __launch_bounds__(256) void transpose_v_kernel(const __bf16* __restrict__ QKV,
                                                          __bf16* __restrict__ Vt) {
  const int t0 = blockIdx.x * 64;
  const int e0 = blockIdx.y * 64;
  const int b = blockIdx.z;
  __shared__ __bf16 T[64][72];
  const int tid = threadIdx.x;
  const int rr = tid >> 3;          // 0..31
  const int cc = (tid & 7) * 8;
  const __bf16* src = QKV + (long long)b * 2048 * 3072 + 2048;
#pragma unroll
  for (int p = 0; p < 2; ++p) {
    int t = rr + p * 32;
    bf16x8 v = *(const bf16x8*)(src + (long long)(t0 + t) * 3072 + e0 + cc);
#pragma unroll
    for (int j = 0; j < 8; ++j) T[t][cc + j] = v[j];
  }
  __syncthreads();
  __bf16* dst = Vt + (long long)b * 1024 * 2048;
#pragma unroll
  for (int p = 0; p < 2; ++p) {
    int e = rr + p * 32;
    bf16x8 ov;
#pragma unroll
    for (int j = 0; j < 8; ++j) ov[j] = T[cc + j][e];
    *(bf16x8*)(dst + (long long)(e0 + e) * 2048 + t0 + cc) = ov;
  }
}

// ---------------- row softmax in place: f32 row[2048] -> bf16 row (first half) ----------------
__global__ __launch_bounds__(256) void softmax_kernel(float* __restrict__ S) {
  const long long row = blockIdx.x;
  float* p = S + row * 2048;
  const int tid = threadIdx.x;
  const int lane = tid & 63, wid = tid >> 6;
  f32x4 v0 = *(const f32x4*)(p + tid * 8);
  f32x4 v1 = *(const f32x4*)(p + tid * 8 + 4);
  float xv[8] = {v0[0], v0[1], v0[2], v0[3], v1[0], v1[1], v1[2], v1[3]};
  float mx = xv[0];
#pragma unroll
  for (int j = 1; j < 8; ++j) mx = fmaxf(mx, xv[j]);
#pragma unroll
  for (int off = 32; off >= 1; off >>= 1) mx = fmaxf(mx, __shfl_xor(mx, off));
  __shared__ float red[8];
  if (lane == 0) red[wid] = mx;
  __syncthreads();
  mx = fmaxf(fmaxf(red[0], red[1]), fmaxf(red[2], red[3]));
  float e[8];
  float sum = 0.f;
#pragma unroll
  for (int j = 0; j < 8; ++j) {
    e[j] = __expf(xv[j] - mx);
    sum += e[j];
  }
#pragma unroll
  for (int off = 32; off >= 1; off >>= 1) sum += __shfl_xor(sum, off);
  if (lane == 0) red[4 + wid] = sum;
  __syncthreads();
  sum = red[4] + red[5] + red[6] + red[7];
  const float inv = 1.0f / sum;
  bf16x8 ov;
#pragma unroll
  for (int j = 0; j < 8; ++j) ov[j] = (__bf16)(e[j] * inv);
  *(bf16x8*)((__bf16*)p + tid * 8) = ov;
}

extern "C" void kernel_launch(void* const* d_in, const int* in_sizes, int n_in,
                              void* d_out, int out_size, void* d_ws, size_t ws_size,
                              hipStream_t stream) {
  (void)in_sizes; (void)n_in; (void)out_size;
  const float* x  = (const float*)d_in[0];
  const float* Wq = (const float*)d_in[1];
  const float* bq = (const float*)d_in[2];
  const float* Wk = (const float*)d_in[3];
  const float* bk = (const float*)d_in[4];
  const float* Wv = (const float*)d_in[5];
  const float* bv = (const float*)d_in[6];
  float* out = (float*)d_out;
  char* ws = (char*)d_ws;
  if (ws_size < 157298688ULL) return;

  __bf16* x16  = (__bf16*)(ws + 0);          // 8192*1024*2      = 16,777,216
  __bf16* Wt   = (__bf16*)(ws + 16777216);   // 3072*1024*2      =  6,291,456
  float*  bqkv = (float*)(ws + 23068672);    // 3072*4           =     12,288
  __bf16* QKV  = (__bf16*)(ws + 23080960);   // 8192*3072*2      = 50,331,648
  __bf16* Vt   = (__bf16*)(ws + 73412608);   // 4*1024*2048*2    = 16,777,216
  float*  S    = (float*)(ws + 90189824);    // 4*2048*2048*4    = 67,108,864

  pack_x_kernel<<<2048, 256, 0, stream>>>(x, x16, 8388608L);
  pack_w_kernel<<<dim3(16, 16, 3), 256, 0, stream>>>(Wq, Wk, Wv, Wt);
  pack_bias_kernel<<<12, 256, 0, stream>>>(bq, bk, bv, bqkv);

  // GEMM1: QKV[8192,3072] = x16[8192,1024] @ Wt^T + bias (bf16 out, Q pre-scaled)
  gemm_bt_kernel<true, true><<<dim3(64 * 24, 1, 1), 256, 0, stream>>>(
      x16, 1024, 0LL, Wt, 1024, 0LL, bqkv, QKV, 3072, 0LL, 24, 16);

  // GEMM2 per batch: S[2048,2048] = Q @ K^T (f32 out)
  gemm_bt_kernel<false, false><<<dim3(16 * 16, 1, 4), 256, 0, stream>>>(
      QKV, 3072, 6291456LL, QKV + 1024, 3072, 6291456LL, nullptr,
      S, 2048, 16777216LL, 16, 16);

  transpose_v_kernel<<<dim3(32, 16, 4), 256, 0, stream>>>(QKV, Vt);

  // softmax rows of S, write bf16 P in place
  softmax_kernel<<<8192, 256, 0, stream>>>(S);

  // GEMM3 per batch: out[2048,1024] = P[2048,2048] @ Vt^T (f32 out)
  gemm_bt_kernel<false, false><<<dim3(16 * 8, 1, 4), 256, 0, stream>>>(
      (const __bf16*)S, 4096, 8388608LL, Vt, 2048, 2097152LL, nullptr,
      out, 1024, 8388608LL, 8, 32);
}

// Round 2
// 206.504 us; speedup vs baseline: 1.0342x; 1.0342x over previous
//
#include <hip/hip_runtime.h>
#include <hip/hip_bf16.h>
#include <stdint.h>

typedef __bf16 bf16x8 __attribute__((ext_vector_type(8)));
typedef __bf16 bf16x4 __attribute__((ext_vector_type(4)));
typedef float f32x4 __attribute__((ext_vector_type(4)));

#define DEV __device__ __forceinline__

DEV void gload_lds16(const void* g, void* l) {
  __builtin_amdgcn_global_load_lds((const __attribute__((address_space(1))) void*)g,
                                   (__attribute__((address_space(3))) void*)l, 16, 0, 0);
}

#define WAITV(n) asm volatile("s_waitcnt vmcnt(" #n ")" ::: "memory")

// ---------------- pack x: f32 -> bf16 ----------------
__global__ __launch_bounds__(256) void pack_x_kernel(const float* __restrict__ x,
                                                     __bf16* __restrict__ o, long n) {
  long i = ((long)blockIdx.x * 256 + threadIdx.x) * 4;
  const long stride = (long)gridDim.x * 256 * 4;
  for (; i < n; i += stride) {
    f32x4 v = *(const f32x4*)(x + i);
    bf16x4 b;
    b[0] = (__bf16)v[0]; b[1] = (__bf16)v[1]; b[2] = (__bf16)v[2]; b[3] = (__bf16)v[3];
    *(bf16x4*)(o + i) = b;
  }
}

// ---------------- pack W: [1024][1024] f32 -> Wt[e][d] bf16 (Wq scaled 1/32) ----------------
__global__ __launch_bounds__(256) void pack_w_kernel(const float* __restrict__ Wq,
                                                     const float* __restrict__ Wk,
                                                     const float* __restrict__ Wv,
                                                     __bf16* __restrict__ Wt) {
  const int w = blockIdx.z;
  const float* W = (w == 0) ? Wq : (w == 1) ? Wk : Wv;
  const float scale = (w == 0) ? 0.03125f : 1.0f;
  const int d0 = blockIdx.x * 64;
  const int e0 = blockIdx.y * 64;
  __shared__ __bf16 T[64][72];
  const int tid = threadIdx.x;
  const int r4 = tid >> 4;
  const int c4 = (tid & 15) * 4;
#pragma unroll
  for (int p = 0; p < 4; ++p) {
    int r = r4 + p * 16;
    f32x4 v = *(const f32x4*)(W + (long)(d0 + r) * 1024 + e0 + c4);
    T[r][c4 + 0] = (__bf16)(v[0] * scale);
    T[r][c4 + 1] = (__bf16)(v[1] * scale);
    T[r][c4 + 2] = (__bf16)(v[2] * scale);
    T[r][c4 + 3] = (__bf16)(v[3] * scale);
  }
  __syncthreads();
  const int e4 = tid >> 3;
  const int dd = (tid & 7) * 8;
#pragma unroll
  for (int p = 0; p < 2; ++p) {
    int e = e4 + p * 32;
    bf16x8 ov;
#pragma unroll
    for (int j = 0; j < 8; ++j) ov[j] = T[dd + j][e];
    *(bf16x8*)(Wt + (long)w * 1048576 + (long)(e0 + e) * 1024 + d0 + dd) = ov;
  }
}

// ---------------- pack bias: concat, bq scaled 1/32, stays f32 ----------------
__global__ __launch_bounds__(256) void pack_bias_kernel(const float* __restrict__ bq,
                                                        const float* __restrict__ bk,
                                                        const float* __restrict__ bv,
                                                        float* __restrict__ o) {
  int i = blockIdx.x * 256 + threadIdx.x;
  if (i < 1024) o[i] = bq[i] * 0.03125f;
  else if (i < 2048) o[i] = bk[i - 1024];
  else if (i < 3072) o[i] = bv[i - 2048];
}

// ---------------- 256-wide-tile GEMM, 4-deep ring pipeline, counted vmcnt ----------------
// C[M,N] = A[M,K] * B[N,K]^T (+bias). BM = M_REP*32, BN = 256, BK = 32.
// 8 waves (2M x 4N); wave owns (M_REP*16) x 64. Ring of 4 K-tile buffers in LDS.
// Stage tile t+3 while computing tile t; one barrier per K-step; vmcnt counted (never 0
// mid-loop). XOR chunk swizzle c ^= (r^(r>>2))&3 applied on global SOURCE and on ds_read
// (both-sides rule); LDS dest of global_load_lds stays linear (wave base + lane*16).
template <int M_REP, bool OUT_BF16, bool BIAS>
__global__ __launch_bounds__(512, 2) void gemm256_kernel(
    const __bf16* __restrict__ A, int lda,
    const __bf16* __restrict__ B, int ldb, long long bBatchStride, int bmShift,
    const float* __restrict__ bias,
    void* __restrict__ C, int ldc,
    int nTiles, int nt) {
  constexpr int BM = M_REP * 32;
  constexpr int A_LOADS = M_REP / 4;     // global_load_lds per thread per tile (A)
  constexpr int LPT = A_LOADS + 2;       // loads per thread per tile (A+B)
  constexpr int ABYTES = BM * 64;        // A region bytes per buffer (BM rows x 64B)
  constexpr int BUFB = ABYTES + 16384;   // + B region (256 rows x 64B)
  __shared__ __attribute__((aligned(128))) char lds[4 * BUFB];

  const int tid = threadIdx.x;
  const int lane = tid & 63;
  const int wid = tid >> 6;
  const int wm = wid >> 2, wn = wid & 3;
  const int lo = lane & 15, hi = lane >> 4;
  const int bm = blockIdx.x / nTiles, bn = blockIdx.x % nTiles;
  const __bf16* Bb = B + (long long)(bm >> bmShift) * bBatchStride;

  // staging addresses: slot s -> LDS row r = s>>2, chunk = s&3; source chunk inverse-swizzled
  const char* gA[A_LOADS]; int lA[A_LOADS];
  const char* gB[2]; int lB[2];
#pragma unroll
  for (int l = 0; l < A_LOADS; ++l) {
    int s = l * 512 + tid, r = s >> 2;
    int c = (s & 3) ^ ((r ^ (r >> 2)) & 3);
    gA[l] = (const char*)(A + (long long)(bm * BM + r) * lda + c * 8);
    lA[l] = s * 16;
  }
#pragma unroll
  for (int l = 0; l < 2; ++l) {
    int s = l * 512 + tid, r = s >> 2;
    int c = (s & 3) ^ ((r ^ (r >> 2)) & 3);
    gB[l] = (const char*)(Bb + (long long)(bn * 256 + r) * ldb + c * 8);
    lB[l] = ABYTES + s * 16;
  }

  // fragment ds_read offsets (swizzled chunk is per-lane constant: cs(row)=cs(lo))
  int aOff[M_REP], bOff[4];
  const int fc = (hi ^ ((lo ^ (lo >> 2)) & 3)) << 4;
#pragma unroll
  for (int mi = 0; mi < M_REP; ++mi)
    aOff[mi] = (wm * (M_REP * 16) + mi * 16 + lo) * 64 + fc;
#pragma unroll
  for (int ni = 0; ni < 4; ++ni)
    bOff[ni] = ABYTES + (wn * 64 + ni * 16 + lo) * 64 + fc;

#define STAGE(t, buf)                                                              \
  do {                                                                             \
    const long long ko_ = (long long)(t) * 64;                                     \
    char* lb_ = lds + (buf) * BUFB;                                                \
    _Pragma("unroll") for (int l = 0; l < A_LOADS; ++l)                            \
        gload_lds16(gA[l] + ko_, lb_ + lA[l]);                                     \
    _Pragma("unroll") for (int l = 0; l < 2; ++l)                                  \
        gload_lds16(gB[l] + ko_, lb_ + lB[l]);                                     \
  } while (0)

  f32x4 acc[M_REP][4] = {};

  // prologue: stage tiles 0,1,2; wait for tile 0 (tiles 1,2 = 2*LPT loads may stay in flight)
  STAGE(0, 0); STAGE(1, 1); STAGE(2, 2);
  if constexpr (LPT == 4) WAITV(8); else WAITV(6);
  __builtin_amdgcn_s_barrier();
  __builtin_amdgcn_sched_barrier(0);

  for (int t = 0; t < nt; ++t) {
    if (t + 3 < nt) STAGE(t + 3, (t + 3) & 3);  // overwrites buffer read in iter t-1 (safe: barrier)
    const char* base = lds + (t & 3) * BUFB;
    bf16x8 av[M_REP], bv[4];
#pragma unroll
    for (int mi = 0; mi < M_REP; ++mi) av[mi] = *(const bf16x8*)(base + aOff[mi]);
#pragma unroll
    for (int ni = 0; ni < 4; ++ni) bv[ni] = *(const bf16x8*)(base + bOff[ni]);
    __builtin_amdgcn_s_setprio(1);
#pragma unroll
    for (int mi = 0; mi < M_REP; ++mi)
#pragma unroll
      for (int ni = 0; ni < 4; ++ni)
        acc[mi][ni] = __builtin_amdgcn_mfma_f32_16x16x32_bf16(av[mi], bv[ni], acc[mi][ni], 0, 0, 0);
    __builtin_amdgcn_s_setprio(0);
    if (t + 1 < nt) {
      // ensure tile t+1 landed; allow tiles t+2, t+3 to remain in flight
      if (t + 3 < nt) { if constexpr (LPT == 4) WAITV(8); else WAITV(6); }
      else if (t + 2 < nt) { if constexpr (LPT == 4) WAITV(4); else WAITV(3); }
      else WAITV(0);
      __builtin_amdgcn_s_barrier();
      __builtin_amdgcn_sched_barrier(0);
    }
  }
#undef STAGE

  // epilogue: C/D map col=lane&15, row=(lane>>4)*4+j
  const long long row0 = (long long)bm * BM + wm * (M_REP * 16) + hi * 4;
  const long long col0 = (long long)bn * 256 + wn * 64 + lo;
#pragma unroll
  for (int ni = 0; ni < 4; ++ni) {
    const long long col = col0 + ni * 16;
    const float bvs = BIAS ? bias[col] : 0.0f;
#pragma unroll
    for (int mi = 0; mi < M_REP; ++mi) {
#pragma unroll
      for (int j = 0; j < 4; ++j) {
        long long row = row0 + mi * 16 + j;
        float v = acc[mi][ni][j] + bvs;
        if (OUT_BF16)
          ((__bf16*)C)[row * ldc + col] = (__bf16)v;
        else
          ((float*)C)[row * ldc + col] = v;
      }
    }
  }
}

// ---------------- transpose V (from QKV col block 2048..3071) -> Vt[b][e][t] ----------------
__global__ __launch_bounds__(256) void transpose_v_kernel(const __bf16* __restrict__ QKV,
                                                          __bf16* __restrict__ Vt) {
  const int t0 = blockIdx.x * 64;
  const int e0 = blockIdx.y * 64;
  const int b = blockIdx.z;
  __shared__ __bf16 T[64][72];
  const int tid = threadIdx.x;
  const int rr = tid >> 3;
  const int cc = (tid & 7) * 8;
  const __bf16* src = QKV + (long long)b * 2048 * 3072 + 2048;
#pragma unroll
  for (int p = 0; p < 2; ++p) {
    int t = rr + p * 32;
    bf16x8 v = *(const bf16x8*)(src + (long long)(t0 + t) * 3072 + e0 + cc);
#pragma unroll
    for (int j = 0; j < 8; ++j) T[t][cc + j] = v[j];
  }
  __syncthreads();
  __bf16* dst = Vt + (long long)b * 1024 * 2048;
#pragma unroll
  for (int p = 0; p < 2; ++p) {
    int e = rr + p * 32;
    bf16x8 ov;
#pragma unroll
    for (int j = 0; j < 8; ++j) ov[j] = T[cc + j][e];
    *(bf16x8*)(dst + (long long)(e0 + e) * 2048 + t0 + cc) = ov;
  }
}

// ---------------- row softmax in place: f32 row[2048] -> bf16 row (first half) ----------------
__global__ __launch_bounds__(256) void softmax_kernel(float* __restrict__ S) {
  const long long row = blockIdx.x;
  float* p = S + row * 2048;
  const int tid = threadIdx.x;
  const int lane = tid & 63, wid = tid >> 6;
  f32x4 v0 = *(const f32x4*)(p + tid * 8);
  f32x4 v1 = *(const f32x4*)(p + tid * 8 + 4);
  float xv[8] = {v0[0], v0[1], v0[2], v0[3], v1[0], v1[1], v1[2], v1[3]};
  float mx = xv[0];
#pragma unroll
  for (int j = 1; j < 8; ++j) mx = fmaxf(mx, xv[j]);
#pragma unroll
  for (int off = 32; off >= 1; off >>= 1) mx = fmaxf(mx, __shfl_xor(mx, off));
  __shared__ float red[8];
  if (lane == 0) red[wid] = mx;
  __syncthreads();
  mx = fmaxf(fmaxf(red[0], red[1]), fmaxf(red[2], red[3]));
  float e[8];
  float sum = 0.f;
#pragma unroll
  for (int j = 0; j < 8; ++j) {
    e[j] = __expf(xv[j] - mx);
    sum += e[j];
  }
#pragma unroll
  for (int off = 32; off >= 1; off >>= 1) sum += __shfl_xor(sum, off);
  if (lane == 0) red[4 + wid] = sum;
  __syncthreads();
  sum = red[4] + red[5] + red[6] + red[7];
  const float inv = 1.0f / sum;
  bf16x8 ov;
#pragma unroll
  for (int j = 0; j < 8; ++j) ov[j] = (__bf16)(e[j] * inv);
  *(bf16x8*)((__bf16*)p + tid * 8) = ov;
}

extern "C" void kernel_launch(void* const* d_in, const int* in_sizes, int n_in,
                              void* d_out, int out_size, void* d_ws, size_t ws_size,
                              hipStream_t stream) {
  (void)in_sizes; (void)n_in; (void)out_size;
  const float* x  = (const float*)d_in[0];
  const float* Wq = (const float*)d_in[1];
  const float* bq = (const float*)d_in[2];
  const float* Wk = (const float*)d_in[3];
  const float* bk = (const float*)d_in[4];
  const float* Wv = (const float*)d_in[5];
  const float* bv = (const float*)d_in[6];
  float* out = (float*)d_out;
  char* ws = (char*)d_ws;
  if (ws_size < 157298688ULL) return;

  __bf16* x16  = (__bf16*)(ws + 0);          // 8192*1024*2      = 16,777,216
  __bf16* Wt   = (__bf16*)(ws + 16777216);   // 3072*1024*2      =  6,291,456
  float*  bqkv = (float*)(ws + 23068672);    // 3072*4           =     12,288
  __bf16* QKV  = (__bf16*)(ws + 23080960);   // 8192*3072*2      = 50,331,648
  __bf16* Vt   = (__bf16*)(ws + 73412608);   // 4*1024*2048*2    = 16,777,216
  float*  S    = (float*)(ws + 90189824);    // 4*2048*2048*4    = 67,108,864

  pack_x_kernel<<<2048, 256, 0, stream>>>(x, x16, 8388608L);
  pack_w_kernel<<<dim3(16, 16, 3), 256, 0, stream>>>(Wq, Wk, Wv, Wt);
  pack_bias_kernel<<<12, 256, 0, stream>>>(bq, bk, bv, bqkv);

  // GEMM1: QKV[8192,3072] = x16 @ Wt^T + bias (bf16 out, Q cols pre-scaled by 1/32)
  gemm256_kernel<8, true, true><<<dim3(32 * 12), 512, 0, stream>>>(
      x16, 1024, Wt, 1024, 0LL, 30, bqkv, QKV, 3072, 12, 32);

  // GEMM2: S[8192,2048] = Q @ K^T (f32 out; M merged across batches, B panel per batch)
  gemm256_kernel<8, false, false><<<dim3(32 * 8), 512, 0, stream>>>(
      QKV, 3072, QKV + 1024, 3072, 6291456LL, 3, nullptr, S, 2048, 8, 32);

  transpose_v_kernel<<<dim3(32, 16, 4), 256, 0, stream>>>(QKV, Vt);

  // softmax rows of S, write bf16 P in place
  softmax_kernel<<<8192, 256, 0, stream>>>(S);

  // GEMM3: out[8192,1024] = P @ Vt^T (f32 out; BM=128 variant for 256-wg grid)
  gemm256_kernel<4, false, false><<<dim3(64 * 4), 512, 0, stream>>>(
      (const __bf16*)S, 4096, Vt, 2048, 2097152LL, 4, nullptr, out, 1024, 4, 64);
}

// Round 3
// 191.954 us; speedup vs baseline: 1.1126x; 1.0758x over previous
//
#include <hip/hip_runtime.h>
#include <hip/hip_bf16.h>
#include <stdint.h>

typedef __bf16 bf16x8 __attribute__((ext_vector_type(8)));
typedef __bf16 bf16x4 __attribute__((ext_vector_type(4)));
typedef float f32x4 __attribute__((ext_vector_type(4)));

#define DEV __device__ __forceinline__

DEV void gload_lds16(const void* g, void* l) {
  __builtin_amdgcn_global_load_lds((const __attribute__((address_space(1))) void*)g,
                                   (__attribute__((address_space(3))) void*)l, 16, 0, 0);
}

#define WAITV(n) asm volatile("s_waitcnt vmcnt(" #n ")" ::: "memory")

// ---------------- pack x: f32 -> bf16 ----------------
__global__ __launch_bounds__(256) void pack_x_kernel(const float* __restrict__ x,
                                                     __bf16* __restrict__ o, long n) {
  long i = ((long)blockIdx.x * 256 + threadIdx.x) * 4;
  const long stride = (long)gridDim.x * 256 * 4;
  for (; i < n; i += stride) {
    f32x4 v = *(const f32x4*)(x + i);
    bf16x4 b;
    b[0] = (__bf16)v[0]; b[1] = (__bf16)v[1]; b[2] = (__bf16)v[2]; b[3] = (__bf16)v[3];
    *(bf16x4*)(o + i) = b;
  }
}

// ---------------- pack W: [1024][1024] f32 -> Wt[e][d] bf16 (Wq scaled 1/32) ----------------
__global__ __launch_bounds__(256) void pack_w_kernel(const float* __restrict__ Wq,
                                                     const float* __restrict__ Wk,
                                                     const float* __restrict__ Wv,
                                                     __bf16* __restrict__ Wt) {
  const int w = blockIdx.z;
  const float* W = (w == 0) ? Wq : (w == 1) ? Wk : Wv;
  const float scale = (w == 0) ? 0.03125f : 1.0f;
  const int d0 = blockIdx.x * 64;
  const int e0 = blockIdx.y * 64;
  __shared__ __bf16 T[64][72];
  const int tid = threadIdx.x;
  const int r4 = tid >> 4;
  const int c4 = (tid & 15) * 4;
#pragma unroll
  for (int p = 0; p < 4; ++p) {
    int r = r4 + p * 16;
    f32x4 v = *(const f32x4*)(W + (long)(d0 + r) * 1024 + e0 + c4);
    T[r][c4 + 0] = (__bf16)(v[0] * scale);
    T[r][c4 + 1] = (__bf16)(v[1] * scale);
    T[r][c4 + 2] = (__bf16)(v[2] * scale);
    T[r][c4 + 3] = (__bf16)(v[3] * scale);
  }
  __syncthreads();
  const int e4 = tid >> 3;
  const int dd = (tid & 7) * 8;
#pragma unroll
  for (int p = 0; p < 2; ++p) {
    int e = e4 + p * 32;
    bf16x8 ov;
#pragma unroll
    for (int j = 0; j < 8; ++j) ov[j] = T[dd + j][e];
    *(bf16x8*)(Wt + (long)w * 1048576 + (long)(e0 + e) * 1024 + d0 + dd) = ov;
  }
}

// ---------------- pack bias: concat, bq scaled 1/32, stays f32 ----------------
__global__ __launch_bounds__(256) void pack_bias_kernel(const float* __restrict__ bq,
                                                        const float* __restrict__ bk,
                                                        const float* __restrict__ bv,
                                                        float* __restrict__ o) {
  int i = blockIdx.x * 256 + threadIdx.x;
  if (i < 1024) o[i] = bq[i] * 0.03125f;
  else if (i < 2048) o[i] = bk[i - 1024];
  else if (i < 3072) o[i] = bv[i - 2048];
}

// ---------------- deep-pipelined GEMM: C[M,N] = A[M,K] * B[N,K]^T (+bias) ----------------
// BN=256, BK=64 (128B rows), 8 waves (2M x 4N). M_REP=8 -> BM=256, ring-2 (128KB LDS),
// stage(t+1) issued at top of tile t (lands ~1 tile before the vmcnt(0)).
// M_REP=4 -> BM=128, ring-3 (144KB LDS), counted vmcnt(6) (never drains mid-loop).
// Swizzle: chunk ^= (row&7), applied on global SOURCE and ds_read addr (both-sides rule);
// gload_lds LDS dest stays linear. This exact pattern measured 0 bank conflicts in R1.
template <int M_REP, int RING, bool OUT_BF16, bool BIAS>
__global__ __launch_bounds__(512, 2) void gemm256_kernel(
    const __bf16* __restrict__ A, int lda,
    const __bf16* __restrict__ B, int ldb, long long bBatchStride, int bmShift,
    const float* __restrict__ bias,
    void* __restrict__ C, int ldc,
    int nTiles, int nt) {
  constexpr int BM = M_REP * 32;
  constexpr int A_LOADS = BM / 64;        // gload_lds per thread per tile (A): 8KB rounds
  constexpr int ABYTES = BM * 128;        // A region bytes per buffer
  constexpr int BUFB = ABYTES + 32768;    // + B region (256 rows x 128B)
  __shared__ __attribute__((aligned(128))) char lds[RING * BUFB];

  const int tid = threadIdx.x;
  const int lane = tid & 63;
  const int wid = tid >> 6;
  const int wm = wid >> 2, wn = wid & 3;  // 2M x 4N waves
  const int lo = lane & 15, hi = lane >> 4;
  const int bm = blockIdx.x / nTiles, bn = blockIdx.x % nTiles;
  const __bf16* Bb = B + (long long)(bm >> bmShift) * bBatchStride;

  // staging: slot s -> LDS row r=s>>3, chunk=s&7; global source chunk inverse-swizzled
  const __bf16* gA[A_LOADS]; int lA[A_LOADS];
  const __bf16* gB[4]; int lB[4];
#pragma unroll
  for (int l = 0; l < A_LOADS; ++l) {
    int s = l * 512 + tid, r = s >> 3;
    int c = (s & 7) ^ (r & 7);
    gA[l] = A + (long long)(bm * BM + r) * lda + c * 8;
    lA[l] = s * 16;
  }
#pragma unroll
  for (int l = 0; l < 4; ++l) {
    int s = l * 512 + tid, r = s >> 3;
    int c = (s & 7) ^ (r & 7);
    gB[l] = Bb + (long long)(bn * 256 + r) * ldb + c * 8;
    lB[l] = ABYTES + s * 16;
  }

  // fragment ds_read byte offsets; per-ks chunk: ks0 -> cx, ks1 -> cx^64
  int aRow[M_REP], bRow[4];
  const int cx = ((hi ^ (lo & 7)) << 4);
#pragma unroll
  for (int mi = 0; mi < M_REP; ++mi)
    aRow[mi] = (wm * (M_REP * 16) + mi * 16 + lo) * 128;
#pragma unroll
  for (int ni = 0; ni < 4; ++ni)
    bRow[ni] = ABYTES + (wn * 64 + ni * 16 + lo) * 128;

#define STAGE(t, buf)                                                \
  do {                                                               \
    const long long ko_ = (long long)(t) * 64;                       \
    char* lb_ = lds + (buf) * BUFB;                                  \
    _Pragma("unroll") for (int l = 0; l < A_LOADS; ++l)              \
        gload_lds16(gA[l] + ko_, lb_ + lA[l]);                       \
    _Pragma("unroll") for (int l = 0; l < 4; ++l)                    \
        gload_lds16(gB[l] + ko_, lb_ + lB[l]);                       \
  } while (0)

  f32x4 acc[M_REP][4] = {};

  // prologue
  if constexpr (RING == 2) {
    STAGE(0, 0);
    WAITV(0);
  } else {
    STAGE(0, 0);
    STAGE(1, 1);
    WAITV(6);  // LPT=6 for M_REP=4: tile1 in flight, tile0 landed
  }
  __builtin_amdgcn_s_barrier();
  __builtin_amdgcn_sched_barrier(0);

  for (int t = 0; t < nt; ++t) {
    // issue next stage early: full HBM latency hides under this tile's compute
    if constexpr (RING == 2) {
      if (t + 1 < nt) STAGE(t + 1, (t + 1) & 1);
    } else {
      if (t + 2 < nt) STAGE(t + 2, (t + 2) % 3);
    }
    const char* base = lds + (t % RING) * BUFB;

    // phase ks=0
    {
      bf16x8 av[M_REP], bv[4];
#pragma unroll
      for (int mi = 0; mi < M_REP; ++mi) av[mi] = *(const bf16x8*)(base + aRow[mi] + cx);
#pragma unroll
      for (int ni = 0; ni < 4; ++ni) bv[ni] = *(const bf16x8*)(base + bRow[ni] + cx);
      __builtin_amdgcn_s_setprio(1);
#pragma unroll
      for (int mi = 0; mi < M_REP; ++mi)
#pragma unroll
        for (int ni = 0; ni < 4; ++ni)
          acc[mi][ni] = __builtin_amdgcn_mfma_f32_16x16x32_bf16(av[mi], bv[ni], acc[mi][ni], 0, 0, 0);
      __builtin_amdgcn_s_setprio(0);
    }
    __builtin_amdgcn_s_barrier();   // mid-tile phase alignment (no waitcnt drain)
    __builtin_amdgcn_sched_barrier(0);
    // phase ks=1
    {
      bf16x8 av[M_REP], bv[4];
#pragma unroll
      for (int mi = 0; mi < M_REP; ++mi) av[mi] = *(const bf16x8*)(base + aRow[mi] + (cx ^ 64));
#pragma unroll
      for (int ni = 0; ni < 4; ++ni) bv[ni] = *(const bf16x8*)(base + bRow[ni] + (cx ^ 64));
      __builtin_amdgcn_s_setprio(1);
#pragma unroll
      for (int mi = 0; mi < M_REP; ++mi)
#pragma unroll
        for (int ni = 0; ni < 4; ++ni)
          acc[mi][ni] = __builtin_amdgcn_mfma_f32_16x16x32_bf16(av[mi], bv[ni], acc[mi][ni], 0, 0, 0);
      __builtin_amdgcn_s_setprio(0);
    }
    // end-of-tile wait: counted for ring-3, lands-long-ago drain for ring-2
    if (t + 1 < nt) {
      if constexpr (RING == 2) {
        WAITV(0);
      } else {
        if (t + 2 < nt) WAITV(6);
        else WAITV(0);
      }
      __builtin_amdgcn_s_barrier();
      __builtin_amdgcn_sched_barrier(0);
    }
  }
#undef STAGE

  // epilogue: C/D map col=lane&15, row=(lane>>4)*4+j
  char* Cb = (char*)C;
  const long long row0 = (long long)bm * BM + wm * (M_REP * 16) + hi * 4;
  const long long col0 = (long long)bn * 256 + wn * 64 + lo;
#pragma unroll
  for (int ni = 0; ni < 4; ++ni) {
    const long long col = col0 + ni * 16;
    const float bvs = BIAS ? bias[col] : 0.0f;
#pragma unroll
    for (int mi = 0; mi < M_REP; ++mi) {
#pragma unroll
      for (int j = 0; j < 4; ++j) {
        long long row = row0 + mi * 16 + j;
        float v = acc[mi][ni][j] + bvs;
        if (OUT_BF16)
          ((__bf16*)Cb)[row * ldc + col] = (__bf16)v;
        else
          ((float*)Cb)[row * ldc + col] = v;
      }
    }
  }
}

// ---------------- transpose V (from QKV col block 2048..3071) -> Vt[b][e][t] ----------------
__global__ __launch_bounds__(256) void transpose_v_kernel(const __bf16* __restrict__ QKV,
                                                          __bf16* __restrict__ Vt) {
  const int t0 = blockIdx.x * 64;
  const int e0 = blockIdx.y * 64;
  const int b = blockIdx.z;
  __shared__ __bf16 T[64][72];
  const int tid = threadIdx.x;
  const int rr = tid >> 3;
  const int cc = (tid & 7) * 8;
  const __bf16* src = QKV + (long long)b * 2048 * 3072 + 2048;
#pragma unroll
  for (int p = 0; p < 2; ++p) {
    int t = rr + p * 32;
    bf16x8 v = *(const bf16x8*)(src + (long long)(t0 + t) * 3072 + e0 + cc);
#pragma unroll
    for (int j = 0; j < 8; ++j) T[t][cc + j] = v[j];
  }
  __syncthreads();
  __bf16* dst = Vt + (long long)b * 1024 * 2048;
#pragma unroll
  for (int p = 0; p < 2; ++p) {
    int e = rr + p * 32;
    bf16x8 ov;
#pragma unroll
    for (int j = 0; j < 8; ++j) ov[j] = T[cc + j][e];
    *(bf16x8*)(dst + (long long)(e0 + e) * 2048 + t0 + cc) = ov;
  }
}

// ---------------- row softmax in place: f32 row[2048] -> bf16 row (first half) ----------------
__global__ __launch_bounds__(256) void softmax_kernel(float* __restrict__ S) {
  const long long row = blockIdx.x;
  float* p = S + row * 2048;
  const int tid = threadIdx.x;
  const int lane = tid & 63, wid = tid >> 6;
  f32x4 v0 = *(const f32x4*)(p + tid * 8);
  f32x4 v1 = *(const f32x4*)(p + tid * 8 + 4);
  float xv[8] = {v0[0], v0[1], v0[2], v0[3], v1[0], v1[1], v1[2], v1[3]};
  float mx = xv[0];
#pragma unroll
  for (int j = 1; j < 8; ++j) mx = fmaxf(mx, xv[j]);
#pragma unroll
  for (int off = 32; off >= 1; off >>= 1) mx = fmaxf(mx, __shfl_xor(mx, off));
  __shared__ float red[8];
  if (lane == 0) red[wid] = mx;
  __syncthreads();
  mx = fmaxf(fmaxf(red[0], red[1]), fmaxf(red[2], red[3]));
  float e[8];
  float sum = 0.f;
#pragma unroll
  for (int j = 0; j < 8; ++j) {
    e[j] = __expf(xv[j] - mx);
    sum += e[j];
  }
#pragma unroll
  for (int off = 32; off >= 1; off >>= 1) sum += __shfl_xor(sum, off);
  if (lane == 0) red[4 + wid] = sum;
  __syncthreads();
  sum = red[4] + red[5] + red[6] + red[7];
  const float inv = 1.0f / sum;
  bf16x8 ov;
#pragma unroll
  for (int j = 0; j < 8; ++j) ov[j] = (__bf16)(e[j] * inv);
  *(bf16x8*)((__bf16*)p + tid * 8) = ov;
}

extern "C" void kernel_launch(void* const* d_in, const int* in_sizes, int n_in,
                              void* d_out, int out_size, void* d_ws, size_t ws_size,
                              hipStream_t stream) {
  (void)in_sizes; (void)n_in; (void)out_size;
  const float* x  = (const float*)d_in[0];
  const float* Wq = (const float*)d_in[1];
  const float* bq = (const float*)d_in[2];
  const float* Wk = (const float*)d_in[3];
  const float* bk = (const float*)d_in[4];
  const float* Wv = (const float*)d_in[5];
  const float* bv = (const float*)d_in[6];
  float* out = (float*)d_out;
  char* ws = (char*)d_ws;
  if (ws_size < 157298688ULL) return;

  __bf16* x16  = (__bf16*)(ws + 0);          // 8192*1024*2      = 16,777,216
  __bf16* Wt   = (__bf16*)(ws + 16777216);   // 3072*1024*2      =  6,291,456
  float*  bqkv = (float*)(ws + 23068672);    // 3072*4           =     12,288
  __bf16* QKV  = (__bf16*)(ws + 23080960);   // 8192*3072*2      = 50,331,648
  __bf16* Vt   = (__bf16*)(ws + 73412608);   // 4*1024*2048*2    = 16,777,216
  float*  S    = (float*)(ws + 90189824);    // 4*2048*2048*4    = 67,108,864

  pack_x_kernel<<<2048, 256, 0, stream>>>(x, x16, 8388608L);
  pack_w_kernel<<<dim3(16, 16, 3), 256, 0, stream>>>(Wq, Wk, Wv, Wt);
  pack_bias_kernel<<<12, 256, 0, stream>>>(bq, bk, bv, bqkv);

  // GEMM1: QKV[8192,3072] = x16 @ Wt^T + bias; BM=128 ring-3, grid 768 = 3 full rounds
  gemm256_kernel<4, 3, true, true><<<dim3(64 * 12), 512, 0, stream>>>(
      x16, 1024, Wt, 1024, 0LL, 30, bqkv, QKV, 3072, 12, 16);

  // GEMM2: S[8192,2048] = Q @ K^T; BM=256 ring-2, grid 256 = 1 full round
  gemm256_kernel<8, 2, false, false><<<dim3(32 * 8), 512, 0, stream>>>(
      QKV, 3072, QKV + 1024, 3072, 6291456LL, 3, nullptr, S, 2048, 8, 16);

  transpose_v_kernel<<<dim3(32, 16, 4), 256, 0, stream>>>(QKV, Vt);

  // softmax rows of S, write bf16 P in place
  softmax_kernel<<<8192, 256, 0, stream>>>(S);

  // GEMM3: out[8192,1024] = P @ Vt^T; BM=128 ring-3, grid 256 = 1 full round
  gemm256_kernel<4, 3, false, false><<<dim3(64 * 4), 512, 0, stream>>>(
      (const __bf16*)S, 4096, Vt, 2048, 2097152LL, 4, nullptr, out, 1024, 4, 32);
}

// Round 4
// 186.075 us; speedup vs baseline: 1.1477x; 1.0316x over previous
//
#include <hip/hip_runtime.h>
#include <hip/hip_bf16.h>
#include <stdint.h>

typedef __bf16 bf16x8 __attribute__((ext_vector_type(8)));
typedef __bf16 bf16x4 __attribute__((ext_vector_type(4)));
typedef float f32x4 __attribute__((ext_vector_type(4)));

#define DEV __device__ __forceinline__

DEV void gload_lds16(const void* g, void* l) {
  __builtin_amdgcn_global_load_lds((const __attribute__((address_space(1))) void*)g,
                                   (__attribute__((address_space(3))) void*)l, 16, 0, 0);
}

#define WAITV(n) asm volatile("s_waitcnt vmcnt(" #n ")" ::: "memory")

// ---------------- pack x: f32 -> bf16 ----------------
__global__ __launch_bounds__(256) void pack_x_kernel(const float* __restrict__ x,
                                                     __bf16* __restrict__ o, long n) {
  long i = ((long)blockIdx.x * 256 + threadIdx.x) * 4;
  const long stride = (long)gridDim.x * 256 * 4;
  for (; i < n; i += stride) {
    f32x4 v = *(const f32x4*)(x + i);
    bf16x4 b;
    b[0] = (__bf16)v[0]; b[1] = (__bf16)v[1]; b[2] = (__bf16)v[2]; b[3] = (__bf16)v[3];
    *(bf16x4*)(o + i) = b;
  }
}

// ---------------- pack W: [1024][1024] f32 -> Wt[e][d] bf16 (Wq scaled 1/32) ----------------
__global__ __launch_bounds__(256) void pack_w_kernel(const float* __restrict__ Wq,
                                                     const float* __restrict__ Wk,
                                                     const float* __restrict__ Wv,
                                                     __bf16* __restrict__ Wt) {
  const int w = blockIdx.z;
  const float* W = (w == 0) ? Wq : (w == 1) ? Wk : Wv;
  const float scale = (w == 0) ? 0.03125f : 1.0f;
  const int d0 = blockIdx.x * 64;
  const int e0 = blockIdx.y * 64;
  __shared__ __bf16 T[64][72];
  const int tid = threadIdx.x;
  const int r4 = tid >> 4;
  const int c4 = (tid & 15) * 4;
#pragma unroll
  for (int p = 0; p < 4; ++p) {
    int r = r4 + p * 16;
    f32x4 v = *(const f32x4*)(W + (long)(d0 + r) * 1024 + e0 + c4);
    T[r][c4 + 0] = (__bf16)(v[0] * scale);
    T[r][c4 + 1] = (__bf16)(v[1] * scale);
    T[r][c4 + 2] = (__bf16)(v[2] * scale);
    T[r][c4 + 3] = (__bf16)(v[3] * scale);
  }
  __syncthreads();
  const int e4 = tid >> 3;
  const int dd = (tid & 7) * 8;
#pragma unroll
  for (int p = 0; p < 2; ++p) {
    int e = e4 + p * 32;
    bf16x8 ov;
#pragma unroll
    for (int j = 0; j < 8; ++j) ov[j] = T[dd + j][e];
    *(bf16x8*)(Wt + (long)w * 1048576 + (long)(e0 + e) * 1024 + d0 + dd) = ov;
  }
}

// ---------------- pack bias: concat, bq scaled 1/32, stays f32 ----------------
__global__ __launch_bounds__(256) void pack_bias_kernel(const float* __restrict__ bq,
                                                        const float* __restrict__ bk,
                                                        const float* __restrict__ bv,
                                                        float* __restrict__ o) {
  int i = blockIdx.x * 256 + threadIdx.x;
  if (i < 1024) o[i] = bq[i] * 0.03125f;
  else if (i < 2048) o[i] = bk[i - 1024];
  else if (i < 3072) o[i] = bv[i - 2048];
}

// ---------------- ring-3 barrier-light GEMM: C[M,N] = A[M,K] * B[N,K]^T (+bias) -------------
// BM=256, BN=128, BK=64. 8 waves (4M x 2N), wave owns 64x64. Ring of 3 K-tile buffers
// (144 KiB): staging tile t+2 writes the buffer freed at end of tile t-1 -> NO intra-tile
// barriers; one raw s_barrier + counted vmcnt(6) per K-tile (wait covers loads issued a
// full tile earlier -> free; never drains mid-loop). Per tile: 4 quadrant phases
// (8 MFMA + 4 ds_read_b128 each, operand reuse in regs), staging gloads spread over
// phases 1-3, setprio(1) around MFMA clusters. chunk^(row&7) both-sides swizzle
// (measured 0 conflicts in R1/R3). Bijective XCD swizzle (grid % 8 == 0 for all calls).
template <bool OUT_BF16, bool BIAS>
__global__ __launch_bounds__(512, 2) void gemm_kernel(
    const __bf16* __restrict__ A, int lda,
    const __bf16* __restrict__ B, int ldb, long long bBatchStride, int bmShift,
    const float* __restrict__ bias,
    void* __restrict__ C, int ldc,
    int nTiles, int nt) {
  constexpr int ABYTES = 256 * 128;       // A region per buffer (256 rows x 128B)
  constexpr int BUFB = ABYTES + 128 * 128;  // + B region (128 rows x 128B) = 48 KiB
  __shared__ __attribute__((aligned(128))) char lds[3 * BUFB];

  const int tid = threadIdx.x;
  const int lane = tid & 63;
  const int wid = tid >> 6;
  const int wm = wid >> 1, wn = wid & 1;  // 4M x 2N waves
  const int lo = lane & 15, hi = lane >> 4;

  // bijective XCD swizzle (gridDim.x % 8 == 0)
  const int cpx = gridDim.x >> 3;
  const int bid = blockIdx.x;
  const int swz = (bid & 7) * cpx + (bid >> 3);
  const int bm = swz / nTiles, bn = swz % nTiles;
  const __bf16* Bb = B + (long long)(bm >> bmShift) * bBatchStride;

  // staging addresses: slot s -> LDS row r=s>>3, chunk=s&7; source chunk inverse-swizzled
  const __bf16* gA[4]; int lA[4];
  const __bf16* gB[2]; int lB[2];
#pragma unroll
  for (int l = 0; l < 4; ++l) {
    int s = l * 512 + tid, r = s >> 3;
    int c = (s & 7) ^ (r & 7);
    gA[l] = A + (long long)(bm * 256 + r) * lda + c * 8;
    lA[l] = s * 16;
  }
#pragma unroll
  for (int l = 0; l < 2; ++l) {
    int s = l * 512 + tid, r = s >> 3;
    int c = (s & 7) ^ (r & 7);
    gB[l] = Bb + (long long)(bn * 128 + r) * ldb + c * 8;
    lB[l] = ABYTES + s * 16;
  }

  // fragment ds_read byte offsets; logical k-chunk hi (ks0) / hi+4 (ks1)
  const int cx = ((hi ^ (lo & 7)) << 4);
  const int aBase = (wm * 64 + lo) * 128;           // + qm*32*128 + mi*16*128
  const int bBase = ABYTES + (wn * 64 + lo) * 128;  // + qn*32*128 + ni*16*128

  f32x4 acc[4][4] = {};

#define STAGE_ALL(tt, buf)                                           \
  do {                                                               \
    const long long ko_ = (long long)(tt) * 64;                      \
    char* lb_ = lds + (buf) * BUFB;                                  \
    _Pragma("unroll") for (int l = 0; l < 4; ++l)                    \
        gload_lds16(gA[l] + ko_, lb_ + lA[l]);                       \
    _Pragma("unroll") for (int l = 0; l < 2; ++l)                    \
        gload_lds16(gB[l] + ko_, lb_ + lB[l]);                       \
  } while (0)

#define LOADA(qm)                                                               \
  _Pragma("unroll") for (int mi = 0; mi < 2; ++mi)                              \
  _Pragma("unroll") for (int ks = 0; ks < 2; ++ks)                              \
      av[mi][ks] = *(const bf16x8*)(base + aBase + ((qm)*32 + mi*16) * 128 +    \
                                    (ks ? (cx ^ 64) : cx));

#define LOADB(qn)                                                               \
  _Pragma("unroll") for (int ni = 0; ni < 2; ++ni)                              \
  _Pragma("unroll") for (int ks = 0; ks < 2; ++ks)                              \
      bv[ni][ks] = *(const bf16x8*)(base + bBase + ((qn)*32 + ni*16) * 128 +    \
                                    (ks ? (cx ^ 64) : cx));

#define MFMA8(qm, qn)                                                           \
  __builtin_amdgcn_s_setprio(1);                                                \
  _Pragma("unroll") for (int mi = 0; mi < 2; ++mi)                              \
  _Pragma("unroll") for (int ni = 0; ni < 2; ++ni)                              \
  _Pragma("unroll") for (int ks = 0; ks < 2; ++ks)                              \
      acc[(qm)*2 + mi][(qn)*2 + ni] = __builtin_amdgcn_mfma_f32_16x16x32_bf16(  \
          av[mi][ks], bv[ni][ks], acc[(qm)*2 + mi][(qn)*2 + ni], 0, 0, 0);      \
  __builtin_amdgcn_s_setprio(0);

  // prologue: stage tiles 0,1; wait tile 0 landed (tile 1's 6 loads stay in flight)
  STAGE_ALL(0, 0);
  STAGE_ALL(1, 1);
  WAITV(6);
  __builtin_amdgcn_s_barrier();
  __builtin_amdgcn_sched_barrier(0);

  for (int t = 0; t < nt; ++t) {
    const char* base = lds + (t % 3) * BUFB;
    char* sb = lds + ((t + 2) % 3) * BUFB;
    const long long ko = (long long)(t + 2) * 64;
    const bool st = (t + 2 < nt);
    bf16x8 av[2][2], bv[2][2];

    // phase 1: quadrant (0,0); stage A chunks 0,1
    LOADA(0); LOADB(0);
    if (st) { gload_lds16(gA[0] + ko, sb + lA[0]); gload_lds16(gA[1] + ko, sb + lA[1]); }
    MFMA8(0, 0);
    // phase 2: quadrant (1,0) — new A, keep B; stage A chunks 2,3
    LOADA(1);
    if (st) { gload_lds16(gA[2] + ko, sb + lA[2]); gload_lds16(gA[3] + ko, sb + lA[3]); }
    MFMA8(1, 0);
    // phase 3: quadrant (1,1) — keep A, new B; stage B chunks 0,1
    LOADB(1);
    if (st) { gload_lds16(gB[0] + ko, sb + lB[0]); gload_lds16(gB[1] + ko, sb + lB[1]); }
    MFMA8(1, 1);
    // phase 4: quadrant (0,1) — new A, keep B
    LOADA(0);
    MFMA8(0, 1);

    // tile boundary: tile t+1 landed (issued during tile t-1); t+2's 6 stay in flight
    if (t + 1 < nt) {
      if (st) WAITV(6); else WAITV(0);
      __builtin_amdgcn_s_barrier();
      __builtin_amdgcn_sched_barrier(0);
    }
  }
#undef STAGE_ALL
#undef LOADA
#undef LOADB
#undef MFMA8

  // epilogue: C/D map col=lane&15, row=(lane>>4)*4+j
  char* Cb = (char*)C;
  const long long row0 = (long long)bm * 256 + wm * 64 + hi * 4;
  const long long col0 = (long long)bn * 128 + wn * 64 + lo;
#pragma unroll
  for (int j2 = 0; j2 < 4; ++j2) {
    const long long col = col0 + (j2 >> 1) * 32 + (j2 & 1) * 16;
    const float bvs = BIAS ? bias[col] : 0.0f;
#pragma unroll
    for (int i2 = 0; i2 < 4; ++i2) {
      const long long row = row0 + (i2 >> 1) * 32 + (i2 & 1) * 16;
#pragma unroll
      for (int j = 0; j < 4; ++j) {
        float v = acc[i2][j2][j] + bvs;
        if (OUT_BF16)
          ((__bf16*)Cb)[(row + j) * ldc + col] = (__bf16)v;
        else
          ((float*)Cb)[(row + j) * ldc + col] = v;
      }
    }
  }
}

// ---------------- transpose V (from QKV col block 2048..3071) -> Vt[b][e][t] ----------------
__global__ __launch_bounds__(256) void transpose_v_kernel(const __bf16* __restrict__ QKV,
                                                          __bf16* __restrict__ Vt) {
  const int t0 = blockIdx.x * 64;
  const int e0 = blockIdx.y * 64;
  const int b = blockIdx.z;
  __shared__ __bf16 T[64][72];
  const int tid = threadIdx.x;
  const int rr = tid >> 3;
  const int cc = (tid & 7) * 8;
  const __bf16* src = QKV + (long long)b * 2048 * 3072 + 2048;
#pragma unroll
  for (int p = 0; p < 2; ++p) {
    int t = rr + p * 32;
    bf16x8 v = *(const bf16x8*)(src + (long long)(t0 + t) * 3072 + e0 + cc);
#pragma unroll
    for (int j = 0; j < 8; ++j) T[t][cc + j] = v[j];
  }
  __syncthreads();
  __bf16* dst = Vt + (long long)b * 1024 * 2048;
#pragma unroll
  for (int p = 0; p < 2; ++p) {
    int e = rr + p * 32;
    bf16x8 ov;
#pragma unroll
    for (int j = 0; j < 8; ++j) ov[j] = T[cc + j][e];
    *(bf16x8*)(dst + (long long)(e0 + e) * 2048 + t0 + cc) = ov;
  }
}

// ---------------- row softmax in place: f32 row[2048] -> bf16 row (first half) ----------------
__global__ __launch_bounds__(256) void softmax_kernel(float* __restrict__ S) {
  const long long row = blockIdx.x;
  float* p = S + row * 2048;
  const int tid = threadIdx.x;
  const int lane = tid & 63, wid = tid >> 6;
  f32x4 v0 = *(const f32x4*)(p + tid * 8);
  f32x4 v1 = *(const f32x4*)(p + tid * 8 + 4);
  float xv[8] = {v0[0], v0[1], v0[2], v0[3], v1[0], v1[1], v1[2], v1[3]};
  float mx = xv[0];
#pragma unroll
  for (int j = 1; j < 8; ++j) mx = fmaxf(mx, xv[j]);
#pragma unroll
  for (int off = 32; off >= 1; off >>= 1) mx = fmaxf(mx, __shfl_xor(mx, off));
  __shared__ float red[8];
  if (lane == 0) red[wid] = mx;
  __syncthreads();
  mx = fmaxf(fmaxf(red[0], red[1]), fmaxf(red[2], red[3]));
  float e[8];
  float sum = 0.f;
#pragma unroll
  for (int j = 0; j < 8; ++j) {
    e[j] = __expf(xv[j] - mx);
    sum += e[j];
  }
#pragma unroll
  for (int off = 32; off >= 1; off >>= 1) sum += __shfl_xor(sum, off);
  if (lane == 0) red[4 + wid] = sum;
  __syncthreads();
  sum = red[4] + red[5] + red[6] + red[7];
  const float inv = 1.0f / sum;
  bf16x8 ov;
#pragma unroll
  for (int j = 0; j < 8; ++j) ov[j] = (__bf16)(e[j] * inv);
  *(bf16x8*)((__bf16*)p + tid * 8) = ov;
}

extern "C" void kernel_launch(void* const* d_in, const int* in_sizes, int n_in,
                              void* d_out, int out_size, void* d_ws, size_t ws_size,
                              hipStream_t stream) {
  (void)in_sizes; (void)n_in; (void)out_size;
  const float* x  = (const float*)d_in[0];
  const float* Wq = (const float*)d_in[1];
  const float* bq = (const float*)d_in[2];
  const float* Wk = (const float*)d_in[3];
  const float* bk = (const float*)d_in[4];
  const float* Wv = (const float*)d_in[5];
  const float* bv = (const float*)d_in[6];
  float* out = (float*)d_out;
  char* ws = (char*)d_ws;
  if (ws_size < 157298688ULL) return;

  __bf16* x16  = (__bf16*)(ws + 0);          // 8192*1024*2      = 16,777,216
  __bf16* Wt   = (__bf16*)(ws + 16777216);   // 3072*1024*2      =  6,291,456
  float*  bqkv = (float*)(ws + 23068672);    // 3072*4           =     12,288
  __bf16* QKV  = (__bf16*)(ws + 23080960);   // 8192*3072*2      = 50,331,648
  __bf16* Vt   = (__bf16*)(ws + 73412608);   // 4*1024*2048*2    = 16,777,216
  float*  S    = (float*)(ws + 90189824);    // 4*2048*2048*4    = 67,108,864

  pack_x_kernel<<<2048, 256, 0, stream>>>(x, x16, 8388608L);
  pack_w_kernel<<<dim3(16, 16, 3), 256, 0, stream>>>(Wq, Wk, Wv, Wt);
  pack_bias_kernel<<<12, 256, 0, stream>>>(bq, bk, bv, bqkv);

  // GEMM1: QKV[8192,3072] = x16 @ Wt^T + bias; grid 32x24 = 768 = 3 full rounds
  gemm_kernel<true, true><<<dim3(768), 512, 0, stream>>>(
      x16, 1024, Wt, 1024, 0LL, 30, bqkv, QKV, 3072, 24, 16);

  // GEMM2: S[8192,2048] = Q @ K^T; grid 32x16 = 512 = 2 full rounds
  gemm_kernel<false, false><<<dim3(512), 512, 0, stream>>>(
      QKV, 3072, QKV + 1024, 3072, 6291456LL, 3, nullptr, S, 2048, 16, 16);

  transpose_v_kernel<<<dim3(32, 16, 4), 256, 0, stream>>>(QKV, Vt);

  // softmax rows of S, write bf16 P in place
  softmax_kernel<<<8192, 256, 0, stream>>>(S);

  // GEMM3: out[8192,1024] = P @ Vt^T; grid 32x8 = 256 = 1 full round
  gemm_kernel<false, false><<<dim3(256), 512, 0, stream>>>(
      (const __bf16*)S, 4096, Vt, 2048, 2097152LL, 3, nullptr, out, 1024, 8, 32);
}